// Round 6
// baseline (619.037 us; speedup 1.0000x reference)
//
#include <hip/hip_runtime.h>
#include <math.h>

#define N_NODES 20000
#define N_EDGES 256000

typedef __attribute__((ext_vector_type(8))) short bf16x8;
typedef __attribute__((ext_vector_type(4))) float f32x4;

__device__ inline unsigned short f2b(float f) {
    unsigned u = __builtin_bit_cast(unsigned, f);
    unsigned r = (u + 0x7fffu + ((u >> 16) & 1u)) >> 16;
    return (unsigned short)r;
}
__device__ inline float b2f(unsigned short s) {
    return __builtin_bit_cast(float, ((unsigned)s) << 16);
}

// ---------------- CSR build ----------------

__global__ void zero_ints(int* __restrict__ a, int n) {
    int i = blockIdx.x * blockDim.x + threadIdx.x;
    if (i < n) a[i] = 0;
}

__global__ void hist_kernel(const int* __restrict__ dst, int* __restrict__ deg) {
    int i = blockIdx.x * blockDim.x + threadIdx.x;
    if (i < N_EDGES) atomicAdd(&deg[dst[i]], 1);
}

#define SCAN_T 1024
#define SCAN_CH 20

__global__ __launch_bounds__(1024) void scan_kernel(const int* __restrict__ deg,
                                                    int* __restrict__ offsets) {
    __shared__ int sums[SCAN_T];
    int tid = threadIdx.x;
    int base = tid * SCAN_CH;
    int vals[SCAN_CH];
    int local = 0;
#pragma unroll
    for (int i = 0; i < SCAN_CH; ++i) {
        int idx = base + i;
        int v = (idx < N_NODES) ? deg[idx] : 0;
        vals[i] = v;
        local += v;
    }
    sums[tid] = local;
    __syncthreads();
    for (int off = 1; off < SCAN_T; off <<= 1) {
        int t = (tid >= off) ? sums[tid - off] : 0;
        __syncthreads();
        sums[tid] += t;
        __syncthreads();
    }
    int run = (tid > 0) ? sums[tid - 1] : 0;
    if (tid == 0) offsets[0] = 0;
#pragma unroll
    for (int i = 0; i < SCAN_CH; ++i) {
        int idx = base + i;
        if (idx < N_NODES) {
            run += vals[i];
            offsets[idx + 1] = run;
        }
    }
}

__global__ void scatter_kernel(const int* __restrict__ dst, const int* __restrict__ src,
                               const int* __restrict__ offsets,
                               int* __restrict__ cursor, int* __restrict__ csrc) {
    int i = blockIdx.x * blockDim.x + threadIdx.x;
    if (i < N_EDGES) {
        int d = dst[i];
        int p = offsets[d] + atomicAdd(&cursor[d], 1);
        csrc[p] = src[i];
    }
}

// ---------------- casts & weight precompute ----------------

__global__ void castx_kernel(const float* __restrict__ in, unsigned short* __restrict__ out, int n4) {
    int i = blockIdx.x * blockDim.x + threadIdx.x;
    if (i < n4) {
        float4 v = ((const float4*)in)[i];
        ushort4 u;
        u.x = f2b(v.x); u.y = f2b(v.y); u.z = f2b(v.z); u.w = f2b(v.w);
        ((ushort4*)out)[i] = u;
    }
}

// Wt[n][k] = bf16(W[k][n])
__global__ void wcast_kernel(const float* __restrict__ W, unsigned short* __restrict__ Wt,
                             int K, int N) {
    int id = blockIdx.x * blockDim.x + threadIdx.x;
    if (id < K * N) {
        int n = id / K, k = id - n * K;
        Wt[id] = f2b(W[(size_t)k * N + n]);
    }
}

// Wal[k*H+h] = sum_f W[k][h*F+f] * a[h*F+f]
__global__ void walcast_kernel(const float* __restrict__ W, const float* __restrict__ a,
                               float* __restrict__ out, int K, int N, int H, int F) {
    int id = blockIdx.x * blockDim.x + threadIdx.x;
    if (id >= K * H) return;
    int k = id / H, h = id - (id / H) * H;
    const float* wrow = W + (size_t)k * N + h * F;
    const float* arow = a + h * F;
    float s = 0.f;
    for (int f = 0; f < F; ++f) s += wrow[f] * arow[f];
    out[id] = s;
}

// ---------------- bf16 MFMA GEMM (per-head block-diagonal) ----------------
// C[M][Cs]: for head h=blockIdx.z, cols [h*Nsub, (h+1)*Nsub), A cols [h*K,(h+1)*K)
// EPI: 0 = plain bf16 store, 1 = bias + ELU + bf16

#define LDK 40  // 32 + 8 pad (bf16 elems)

template <int EPI>
__global__ __launch_bounds__(256) void gemm_mfma(
    const unsigned short* __restrict__ A, const unsigned short* __restrict__ Bt,
    unsigned short* __restrict__ C, const float* __restrict__ bias,
    int M, int Nsub, int K, int As, int Cs) {
    __shared__ short AsL[128 * LDK];
    __shared__ short BsL[64 * LDK];
    int tid = threadIdx.x;
    int h = blockIdx.z;
    int aoff = h * K;
    int nbase = h * Nsub;
    int m0 = blockIdx.y * 128, n0l = blockIdx.x * 64;
    int lane = tid & 63, wid = tid >> 6;
    int wm = wid >> 1, wn = wid & 1;
    int r16 = lane & 15, kg = lane >> 4, k8 = kg * 8;

    f32x4 zero4 = {0.f, 0.f, 0.f, 0.f};
    f32x4 acc[4][2];
#pragma unroll
    for (int m = 0; m < 4; ++m)
#pragma unroll
        for (int nn = 0; nn < 2; ++nn) acc[m][nn] = zero4;

    bf16x8 zv = {0, 0, 0, 0, 0, 0, 0, 0};

    for (int k0 = 0; k0 < K; k0 += 32) {
#pragma unroll
        for (int i = 0; i < 2; ++i) {
            int c = tid + i * 256;
            int row = c >> 2, off = (c & 3) * 8;
            bf16x8 v = zv;
            int gr = m0 + row, gc = k0 + off;
            if (gr < M && gc + 8 <= K)
                v = *(const bf16x8*)(const void*)(A + (size_t)gr * As + aoff + gc);
            *(bf16x8*)(void*)(&AsL[row * LDK + off]) = v;
        }
        {
            int row = tid >> 2, off = (tid & 3) * 8;
            bf16x8 v = zv;
            int lr = n0l + row, gc = k0 + off;
            if (lr < Nsub && gc + 8 <= K)
                v = *(const bf16x8*)(const void*)(Bt + (size_t)(nbase + lr) * K + gc);
            *(bf16x8*)(void*)(&BsL[row * LDK + off]) = v;
        }
        __syncthreads();
        bf16x8 a[4], b[2];
#pragma unroll
        for (int m = 0; m < 4; ++m)
            a[m] = *(const bf16x8*)(const void*)(&AsL[(wm * 64 + m * 16 + r16) * LDK + k8]);
#pragma unroll
        for (int nn = 0; nn < 2; ++nn)
            b[nn] = *(const bf16x8*)(const void*)(&BsL[(wn * 32 + nn * 16 + r16) * LDK + k8]);
#pragma unroll
        for (int m = 0; m < 4; ++m)
#pragma unroll
            for (int nn = 0; nn < 2; ++nn)
                acc[m][nn] = __builtin_amdgcn_mfma_f32_16x16x32_bf16(a[m], b[nn], acc[m][nn], 0, 0, 0);
        __syncthreads();
    }
#pragma unroll
    for (int m = 0; m < 4; ++m) {
        int row_base = m0 + wm * 64 + m * 16 + kg * 4;
#pragma unroll
        for (int nn = 0; nn < 2; ++nn) {
            int col_l = n0l + wn * 32 + nn * 16 + r16;
            if (col_l < Nsub) {
                int col = nbase + col_l;
                float bv = (EPI == 1) ? bias[col] : 0.f;
#pragma unroll
                for (int r = 0; r < 4; ++r) {
                    int row = row_base + r;
                    if (row < M) {
                        float v = acc[m][nn][r];
                        if (EPI == 1) {
                            v += bv;
                            v = v > 0.f ? v : expm1f(v);
                        }
                        C[(size_t)row * Cs + col] = f2b(v);
                    }
                }
            }
        }
    }
}

// ---------------- el/er from input features via Wal/War [K][4] ----------------
__global__ __launch_bounds__(256) void elr2_kernel(
    const unsigned short* __restrict__ x, const float* __restrict__ Wal,
    const float* __restrict__ War, float* __restrict__ el, float* __restrict__ er,
    int K, int nnodes) {
    int n = blockIdx.x * 4 + (threadIdx.x >> 6);
    if (n >= nnodes) return;
    int lane = threadIdx.x & 63;
    const unsigned* row = (const unsigned*)(const void*)(x + (size_t)n * K);
    int K2 = K >> 1;
    float sl[4] = {0.f, 0.f, 0.f, 0.f}, sr[4] = {0.f, 0.f, 0.f, 0.f};
    for (int i = lane; i < K2; i += 64) {
        unsigned u = row[i];
        float v0 = b2f((unsigned short)(u & 0xffffu));
        float v1 = b2f((unsigned short)(u >> 16));
        float4 wa0 = ((const float4*)Wal)[2 * i];
        float4 wa1 = ((const float4*)Wal)[2 * i + 1];
        float4 wr0 = ((const float4*)War)[2 * i];
        float4 wr1 = ((const float4*)War)[2 * i + 1];
        sl[0] += v0 * wa0.x + v1 * wa1.x;
        sl[1] += v0 * wa0.y + v1 * wa1.y;
        sl[2] += v0 * wa0.z + v1 * wa1.z;
        sl[3] += v0 * wa0.w + v1 * wa1.w;
        sr[0] += v0 * wr0.x + v1 * wr1.x;
        sr[1] += v0 * wr0.y + v1 * wr1.y;
        sr[2] += v0 * wr0.z + v1 * wr1.z;
        sr[3] += v0 * wr0.w + v1 * wr1.w;
    }
#pragma unroll
    for (int off = 32; off; off >>= 1) {
#pragma unroll
        for (int h = 0; h < 4; ++h) {
            sl[h] += __shfl_xor(sl[h], off);
            sr[h] += __shfl_xor(sr[h], off);
        }
    }
    if (lane == 0) {
        *(float4*)(el + (size_t)n * 4) = make_float4(sl[0], sl[1], sl[2], sl[3]);
        *(float4*)(er + (size_t)n * 4) = make_float4(sr[0], sr[1], sr[2], sr[3]);
    }
}

// ---------------- attention dots on projected h (layer 3, H=1) ----------------
__global__ void elr_kernel(const unsigned short* __restrict__ h, const float* __restrict__ al,
                           const float* __restrict__ ar, float* __restrict__ el,
                           float* __restrict__ er, int H, int F) {
    int n = blockIdx.x;
    int lane = threadIdx.x & 63;
    int hh = threadIdx.x >> 6;
    const unsigned* row = (const unsigned*)(const void*)(h + (size_t)n * H * F + (size_t)hh * F);
    int F2 = F >> 1;
    float sl = 0.f, sr = 0.f;
    for (int f = lane; f < F2; f += 64) {
        unsigned u = row[f];
        float v0 = b2f((unsigned short)(u & 0xffffu));
        float v1 = b2f((unsigned short)(u >> 16));
        int c = hh * F + 2 * f;
        sl += v0 * al[c] + v1 * al[c + 1];
        sr += v0 * ar[c] + v1 * ar[c + 1];
    }
#pragma unroll
    for (int off = 32; off; off >>= 1) {
        sl += __shfl_down(sl, off);
        sr += __shfl_down(sr, off);
    }
    if (lane == 0) {
        el[n * H + hh] = sl;
        er[n * H + hh] = sr;
    }
}

// ---------------- fused edge-score + softmax -> alpha (CSR order) ----------------
template <int H>
__global__ __launch_bounds__(256) void alpha_kernel(
    const float* __restrict__ el, const float* __restrict__ er,
    const int* __restrict__ csrc, const int* __restrict__ offsets,
    float* __restrict__ alpha, int nnodes) {
    int n = blockIdx.x * 4 + (threadIdx.x >> 6);
    if (n >= nnodes) return;
    int lane = threadIdx.x & 63;
    int start = offsets[n], deg = offsets[n + 1] - start;
    if (deg == 0) return;
    float ern[H];
#pragma unroll
    for (int h = 0; h < H; ++h) ern[h] = er[n * H + h];

    if (deg <= 64) {
        bool act = lane < deg;
        float sh[H];
#pragma unroll
        for (int h = 0; h < H; ++h) sh[h] = -3.402823466e38f;
        if (act) {
            int sc = csrc[start + lane];
            if constexpr (H == 4) {
                float4 e4 = *(const float4*)(el + (size_t)sc * 4);
                float tv[4] = {e4.x, e4.y, e4.z, e4.w};
#pragma unroll
                for (int h = 0; h < 4; ++h) {
                    float v = tv[h] + ern[h];
                    sh[h] = v > 0.f ? v : 0.2f * v;
                }
            } else {
#pragma unroll
                for (int h = 0; h < H; ++h) {
                    float v = el[sc * H + h] + ern[h];
                    sh[h] = v > 0.f ? v : 0.2f * v;
                }
            }
        }
        float m[H], e[H], s[H];
#pragma unroll
        for (int h = 0; h < H; ++h) {
            m[h] = sh[h];
#pragma unroll
            for (int off = 32; off; off >>= 1) m[h] = fmaxf(m[h], __shfl_xor(m[h], off));
        }
#pragma unroll
        for (int h = 0; h < H; ++h) {
            e[h] = act ? expf(sh[h] - m[h]) : 0.f;
            s[h] = e[h];
#pragma unroll
            for (int off = 32; off; off >>= 1) s[h] += __shfl_xor(s[h], off);
        }
        if (act) {
            if constexpr (H == 4) {
                float4 o;
                o.x = e[0] / (s[0] + 1e-9f);
                o.y = e[1] / (s[1] + 1e-9f);
                o.z = e[2] / (s[2] + 1e-9f);
                o.w = e[3] / (s[3] + 1e-9f);
                *(float4*)(alpha + (size_t)(start + lane) * 4) = o;
            } else {
#pragma unroll
                for (int h = 0; h < H; ++h)
                    alpha[(size_t)(start + lane) * H + h] = e[h] / (s[h] + 1e-9f);
            }
        }
    } else {
        float m[H], s[H];
#pragma unroll
        for (int h = 0; h < H; ++h) { m[h] = -3.402823466e38f; s[h] = 0.f; }
        for (int c0 = 0; c0 < deg; c0 += 64) {
            if (c0 + lane < deg) {
                int sc = csrc[start + c0 + lane];
#pragma unroll
                for (int h = 0; h < H; ++h) {
                    float v = el[sc * H + h] + ern[h];
                    v = v > 0.f ? v : 0.2f * v;
                    m[h] = fmaxf(m[h], v);
                }
            }
        }
#pragma unroll
        for (int h = 0; h < H; ++h)
#pragma unroll
            for (int off = 32; off; off >>= 1) m[h] = fmaxf(m[h], __shfl_xor(m[h], off));
        for (int c0 = 0; c0 < deg; c0 += 64) {
            if (c0 + lane < deg) {
                int sc = csrc[start + c0 + lane];
#pragma unroll
                for (int h = 0; h < H; ++h) {
                    float v = el[sc * H + h] + ern[h];
                    v = v > 0.f ? v : 0.2f * v;
                    s[h] += expf(v - m[h]);
                }
            }
        }
#pragma unroll
        for (int h = 0; h < H; ++h)
#pragma unroll
            for (int off = 32; off; off >>= 1) s[h] += __shfl_xor(s[h], off);
        for (int c0 = 0; c0 < deg; c0 += 64) {
            if (c0 + lane < deg) {
                int sc = csrc[start + c0 + lane];
#pragma unroll
                for (int h = 0; h < H; ++h) {
                    float v = el[sc * H + h] + ern[h];
                    v = v > 0.f ? v : 0.2f * v;
                    alpha[(size_t)(start + c0 + lane) * H + h] = expf(v - m[h]) / (s[h] + 1e-9f);
                }
            }
        }
    }
}

// ---------------- flipped aggregation: out[n][H][K] = sum_e alpha[e][h] * x[src_e][:] ----------------
// NC = K/8 chunks, H=4 heads, P edge groups. Raw sum (no bias/act), bf16 out.
template <int NC, int H, int P>
__global__ __launch_bounds__(256) void aggflip_kernel(
    const unsigned short* __restrict__ xC, const float* __restrict__ alpha,
    const int* __restrict__ offsets, const int* __restrict__ csrc,
    unsigned short* __restrict__ out) {
    constexpr int K = NC * 8;
    int n = blockIdx.x;
    int tid = threadIdx.x;
    int start = offsets[n], deg = offsets[n + 1] - start;

    __shared__ int s_src[64];
    __shared__ float s_alpha[64 * H];
    __shared__ float s_part[(P - 1) * NC * H * 8];

    bool active = tid < NC * P;
    int slot = tid % NC;
    int q = tid / NC;
    float acc[H][8];
#pragma unroll
    for (int h = 0; h < H; ++h)
#pragma unroll
        for (int j = 0; j < 8; ++j) acc[h][j] = 0.f;

    for (int c0 = 0; c0 < deg; c0 += 64) {
        int cn = min(64, deg - c0);
        if (tid < cn) {
            s_src[tid] = csrc[start + c0 + tid];
            float4 a4 = *(const float4*)(alpha + (size_t)(start + c0 + tid) * 4);
            *(float4*)(&s_alpha[tid * 4]) = a4;
        }
        __syncthreads();
        if (active) {
            for (int k = q; k < cn; k += P) {
                const unsigned short* row = xC + (size_t)s_src[k] * K;
                bf16x8 v = *(const bf16x8*)(const void*)(row + slot * 8);
                float xv[8];
#pragma unroll
                for (int j = 0; j < 8; ++j) xv[j] = b2f((unsigned short)v[j]);
#pragma unroll
                for (int h = 0; h < H; ++h) {
                    float a = s_alpha[k * H + h];
#pragma unroll
                    for (int j = 0; j < 8; ++j) acc[h][j] += xv[j] * a;
                }
            }
        }
        __syncthreads();
    }

    if (active && q > 0) {
#pragma unroll
        for (int h = 0; h < H; ++h)
#pragma unroll
            for (int j = 0; j < 8; ++j)
                s_part[(((q - 1) * NC + slot) * H + h) * 8 + j] = acc[h][j];
    }
    __syncthreads();
    if (tid < NC) {
        for (int qq = 1; qq < P; ++qq)
#pragma unroll
            for (int h = 0; h < H; ++h)
#pragma unroll
                for (int j = 0; j < 8; ++j)
                    acc[h][j] += s_part[(((qq - 1) * NC + slot) * H + h) * 8 + j];
#pragma unroll
        for (int h = 0; h < H; ++h) {
            bf16x8 u;
#pragma unroll
            for (int j = 0; j < 8; ++j) u[j] = (short)f2b(acc[h][j]);
            *(bf16x8*)(void*)(out + ((size_t)n * H + h) * K + slot * 8) = u;
        }
    }
}

// ---------------- direct aggregation on projected h (layer 3) ----------------
template <int ACT, int H, int NC, int P>
__global__ __launch_bounds__(256) void aggregate_kernel(
    const unsigned short* __restrict__ hC, const float* __restrict__ alpha,
    const int* __restrict__ offsets, const int* __restrict__ csrc,
    const float* __restrict__ bias, void* __restrict__ out) {
    constexpr int HF = NC * 8;
    constexpr int F = HF / H;
    int n = blockIdx.x;
    int tid = threadIdx.x;
    int start = offsets[n], deg = offsets[n + 1] - start;

    __shared__ int s_src[64];
    __shared__ float s_alpha[64 * H];
    __shared__ float s_part[(P > 1 ? (P - 1) : 1) * NC * 8];

    bool active = tid < NC * P;
    int slot = tid % NC;
    int q = tid / NC;
    int h0 = (slot * 8) / F, h1 = (slot * 8 + 7) / F;
    int split = (h0 == h1) ? 8 : (h1 * F - slot * 8);
    float acc[8] = {0.f, 0.f, 0.f, 0.f, 0.f, 0.f, 0.f, 0.f};

    for (int c0 = 0; c0 < deg; c0 += 64) {
        int cn = min(64, deg - c0);
        if (tid < cn) {
            s_src[tid] = csrc[start + c0 + tid];
            if constexpr (H == 4) {
                float4 a4 = *(const float4*)(alpha + (size_t)(start + c0 + tid) * 4);
                *(float4*)(&s_alpha[tid * 4]) = a4;
            } else {
                s_alpha[tid] = alpha[start + c0 + tid];
            }
        }
        __syncthreads();
        if (active) {
            for (int k = q; k < cn; k += P) {
                const unsigned short* row = hC + (size_t)s_src[k] * HF;
                bf16x8 v = *(const bf16x8*)(const void*)(row + slot * 8);
                float a0 = s_alpha[k * H + h0];
                float a1 = s_alpha[k * H + h1];
#pragma unroll
                for (int j = 0; j < 8; ++j) {
                    float a = (j < split) ? a0 : a1;
                    acc[j] += b2f((unsigned short)v[j]) * a;
                }
            }
        }
        __syncthreads();
    }

    if constexpr (P > 1) {
        if (active && q > 0) {
#pragma unroll
            for (int j = 0; j < 8; ++j) s_part[((q - 1) * NC + slot) * 8 + j] = acc[j];
        }
        __syncthreads();
        if (tid < NC) {
            for (int qq = 1; qq < P; ++qq)
#pragma unroll
                for (int j = 0; j < 8; ++j) acc[j] += s_part[((qq - 1) * NC + slot) * 8 + j];
        }
    }

    if (tid < NC) {
        float4 bA = *(const float4*)(bias + slot * 8);
        float4 bB = *(const float4*)(bias + slot * 8 + 4);
        float bb[8] = {bA.x, bA.y, bA.z, bA.w, bB.x, bB.y, bB.z, bB.w};
        float v[8];
#pragma unroll
        for (int j = 0; j < 8; ++j) v[j] = acc[j] + bb[j];
        if (ACT == 0) {
            bf16x8 u;
#pragma unroll
            for (int j = 0; j < 8; ++j) {
                float w = v[j] > 0.f ? v[j] : expm1f(v[j]);
                u[j] = (short)f2b(w);
            }
            *(bf16x8*)(void*)((unsigned short*)out + (size_t)n * HF + slot * 8) = u;
        } else {
            float4 oA, oB;
            oA.x = 1.f / (1.f + expf(-v[0]));
            oA.y = 1.f / (1.f + expf(-v[1]));
            oA.z = 1.f / (1.f + expf(-v[2]));
            oA.w = 1.f / (1.f + expf(-v[3]));
            oB.x = 1.f / (1.f + expf(-v[4]));
            oB.y = 1.f / (1.f + expf(-v[5]));
            oB.z = 1.f / (1.f + expf(-v[6]));
            oB.w = 1.f / (1.f + expf(-v[7]));
            float* op = (float*)out + (size_t)n * HF + slot * 8;
            *(float4*)op = oA;
            *(float4*)(op + 4) = oB;
        }
    }
}

// ---------------- launch ----------------

extern "C" void kernel_launch(void* const* d_in, const int* in_sizes, int n_in,
                              void* d_out, int out_size, void* d_ws, size_t ws_size,
                              hipStream_t stream) {
    const float* x   = (const float*)d_in[0];
    const int*   src = (const int*)d_in[1];
    const int*   dst = (const int*)d_in[2];
    const float* W1  = (const float*)d_in[3];
    const float* al1 = (const float*)d_in[4];
    const float* ar1 = (const float*)d_in[5];
    const float* b1  = (const float*)d_in[6];
    const float* W2  = (const float*)d_in[7];
    const float* al2 = (const float*)d_in[8];
    const float* ar2 = (const float*)d_in[9];
    const float* b2  = (const float*)d_in[10];
    const float* W3  = (const float*)d_in[11];
    const float* al3 = (const float*)d_in[12];
    const float* ar3 = (const float*)d_in[13];
    const float* b3  = (const float*)d_in[14];
    float* out = (float*)d_out;

    char* ws = (char*)d_ws;
    size_t off = 0;
    auto alloc = [&](size_t bytes) -> char* {
        char* p = ws + off;
        off += (bytes + 255) & ~(size_t)255;
        return p;
    };
    int* offsets = (int*)alloc((N_NODES + 1) * sizeof(int));
    int* cursor  = (int*)alloc(N_NODES * sizeof(int));
    int* deg     = (int*)alloc(N_NODES * sizeof(int));
    int* csrc    = (int*)alloc(N_EDGES * sizeof(int));
    float* el    = (float*)alloc((size_t)N_NODES * 4 * sizeof(float));
    float* er    = (float*)alloc((size_t)N_NODES * 4 * sizeof(float));
    float* alpha = (float*)alloc((size_t)N_EDGES * 4 * sizeof(float));
    float* Wal   = (float*)alloc((size_t)400 * 4 * sizeof(float));
    float* War   = (float*)alloc((size_t)400 * 4 * sizeof(float));
    unsigned short* Wt   = (unsigned short*)alloc((size_t)800 * 400 * 2);
    unsigned short* bufY = (unsigned short*)alloc((size_t)N_NODES * 400 * 2);   // L1 out
    unsigned short* bufZ = (unsigned short*)alloc((size_t)N_NODES * 800 * 2);   // L2 out
    unsigned short* bufX = (unsigned short*)alloc((size_t)N_NODES * 128 * 2);   // x bf16; reused as h3
    unsigned short* agg  = (unsigned short*)alloc((size_t)N_NODES * 1600 * 2);  // aggX / aggY arena

    // CSR build
    zero_ints<<<(N_NODES + 255) / 256, 256, 0, stream>>>(deg, N_NODES);
    zero_ints<<<(N_NODES + 255) / 256, 256, 0, stream>>>(cursor, N_NODES);
    hist_kernel<<<(N_EDGES + 255) / 256, 256, 0, stream>>>(dst, deg);
    scan_kernel<<<1, SCAN_T, 0, stream>>>(deg, offsets);
    scatter_kernel<<<(N_EDGES + 255) / 256, 256, 0, stream>>>(dst, src, offsets, cursor, csrc);

    // x -> bf16
    castx_kernel<<<(N_NODES * 128 / 4 + 255) / 256, 256, 0, stream>>>(x, bufX, N_NODES * 128 / 4);

    // ---- layer 1 (flipped): agg(x) per head, then per-head GEMM + bias + ELU ----
    {
        int K = 128, N = 400, H = 4, F = 100;
        walcast_kernel<<<(K * H + 255) / 256, 256, 0, stream>>>(W1, al1, Wal, K, N, H, F);
        walcast_kernel<<<(K * H + 255) / 256, 256, 0, stream>>>(W1, ar1, War, K, N, H, F);
        elr2_kernel<<<(N_NODES + 3) / 4, 256, 0, stream>>>(bufX, Wal, War, el, er, K, N_NODES);
        alpha_kernel<4><<<(N_NODES + 3) / 4, 256, 0, stream>>>(el, er, csrc, offsets, alpha, N_NODES);
        aggflip_kernel<16, 4, 8><<<N_NODES, 256, 0, stream>>>(bufX, alpha, offsets, csrc, agg);
        wcast_kernel<<<(K * N + 255) / 256, 256, 0, stream>>>(W1, Wt, K, N);
        dim3 grid((F + 63) / 64, (N_NODES + 127) / 128, H);
        gemm_mfma<1><<<grid, 256, 0, stream>>>(agg, Wt, bufY, b1, N_NODES, F, K, H * K, N);
    }
    // ---- layer 2 (flipped) ----
    {
        int K = 400, N = 800, H = 4, F = 200;
        walcast_kernel<<<(K * H + 255) / 256, 256, 0, stream>>>(W2, al2, Wal, K, N, H, F);
        walcast_kernel<<<(K * H + 255) / 256, 256, 0, stream>>>(W2, ar2, War, K, N, H, F);
        elr2_kernel<<<(N_NODES + 3) / 4, 256, 0, stream>>>(bufY, Wal, War, el, er, K, N_NODES);
        alpha_kernel<4><<<(N_NODES + 3) / 4, 256, 0, stream>>>(el, er, csrc, offsets, alpha, N_NODES);
        aggflip_kernel<50, 4, 5><<<N_NODES, 256, 0, stream>>>(bufY, alpha, offsets, csrc, agg);
        wcast_kernel<<<(K * N + 255) / 256, 256, 0, stream>>>(W2, Wt, K, N);
        dim3 grid((F + 63) / 64, (N_NODES + 127) / 128, H);
        gemm_mfma<1><<<grid, 256, 0, stream>>>(agg, Wt, bufZ, b2, N_NODES, F, K, H * K, N);
    }
    // ---- layer 3 (direct): GEMM -> elr -> alpha -> aggregate + bias + sigmoid ----
    {
        int K = 800, N = 64, F = 64;
        wcast_kernel<<<(K * N + 255) / 256, 256, 0, stream>>>(W3, Wt, K, N);
        dim3 grid(1, (N_NODES + 127) / 128, 1);
        gemm_mfma<0><<<grid, 256, 0, stream>>>(bufZ, Wt, bufX, nullptr, N_NODES, N, K, K, N);
        elr_kernel<<<N_NODES, 64, 0, stream>>>(bufX, al3, ar3, el, er, 1, F);
        alpha_kernel<1><<<(N_NODES + 3) / 4, 256, 0, stream>>>(el, er, csrc, offsets, alpha, N_NODES);
        aggregate_kernel<1, 1, 8, 8><<<N_NODES, 256, 0, stream>>>(bufX, alpha, offsets, csrc, b3, out);
    }
}

// Round 9
// 496.040 us; speedup vs baseline: 1.2480x; 1.2480x over previous
//
#include <hip/hip_runtime.h>
#include <math.h>

#define N_NODES 20000
#define N_EDGES 256000

typedef __attribute__((ext_vector_type(8))) short bf16x8;
typedef __attribute__((ext_vector_type(4))) float f32x4;

__device__ inline unsigned short f2b(float f) {
    unsigned u = __builtin_bit_cast(unsigned, f);
    unsigned r = (u + 0x7fffu + ((u >> 16) & 1u)) >> 16;
    return (unsigned short)r;
}
__device__ inline float b2f(unsigned short s) {
    return __builtin_bit_cast(float, ((unsigned)s) << 16);
}

// ---------------- CSR build ----------------

__global__ void zero_ints(int* __restrict__ a, int n) {
    int i = blockIdx.x * blockDim.x + threadIdx.x;
    if (i < n) a[i] = 0;
}

__global__ void hist_kernel(const int* __restrict__ dst, int* __restrict__ deg) {
    int i = blockIdx.x * blockDim.x + threadIdx.x;
    if (i < N_EDGES) atomicAdd(&deg[dst[i]], 1);
}

#define SCAN_T 1024
#define SCAN_CH 20

__global__ __launch_bounds__(1024) void scan_kernel(const int* __restrict__ deg,
                                                    int* __restrict__ offsets) {
    __shared__ int sums[SCAN_T];
    int tid = threadIdx.x;
    int base = tid * SCAN_CH;
    int vals[SCAN_CH];
    int local = 0;
#pragma unroll
    for (int i = 0; i < SCAN_CH; ++i) {
        int idx = base + i;
        int v = (idx < N_NODES) ? deg[idx] : 0;
        vals[i] = v;
        local += v;
    }
    sums[tid] = local;
    __syncthreads();
    for (int off = 1; off < SCAN_T; off <<= 1) {
        int t = (tid >= off) ? sums[tid - off] : 0;
        __syncthreads();
        sums[tid] += t;
        __syncthreads();
    }
    int run = (tid > 0) ? sums[tid - 1] : 0;
    if (tid == 0) offsets[0] = 0;
#pragma unroll
    for (int i = 0; i < SCAN_CH; ++i) {
        int idx = base + i;
        if (idx < N_NODES) {
            run += vals[i];
            offsets[idx + 1] = run;
        }
    }
}

__global__ void scatter_kernel(const int* __restrict__ dst, const int* __restrict__ src,
                               const int* __restrict__ offsets,
                               int* __restrict__ cursor, int* __restrict__ csrc) {
    int i = blockIdx.x * blockDim.x + threadIdx.x;
    if (i < N_EDGES) {
        int d = dst[i];
        int p = offsets[d] + atomicAdd(&cursor[d], 1);
        csrc[p] = src[i];
    }
}

// ---------------- casts ----------------

__global__ void castx_kernel(const float* __restrict__ in, unsigned short* __restrict__ out, int n4) {
    int i = blockIdx.x * blockDim.x + threadIdx.x;
    if (i < n4) {
        float4 v = ((const float4*)in)[i];
        ushort4 u;
        u.x = f2b(v.x); u.y = f2b(v.y); u.z = f2b(v.z); u.w = f2b(v.w);
        ((ushort4*)out)[i] = u;
    }
}

// Wt[n][k] = bf16(W[k][n]); W is [K][N] row-major
__global__ void wcast_kernel(const float* __restrict__ W, unsigned short* __restrict__ Wt,
                             int K, int N) {
    int id = blockIdx.x * blockDim.x + threadIdx.x;
    if (id < K * N) {
        int n = id / K, k = id - n * K;
        Wt[id] = f2b(W[(size_t)k * N + n]);
    }
}

// ---------------- bf16 MFMA GEMM: C[M,N](bf16) = A[M,K] * Bt[N,K]^T ----------------
// 128xBN tile, BK=32, 4 waves (2x2); per-wave 64 x BN/2 (4 x BN/32 frags of 16x16x32)

#define LDK 40  // 32 + 8 pad (bf16 elems); 80B row stride keeps ds_read_b128 ~conflict-free

template <int BN>
__global__ __launch_bounds__(256) void gemm_mfma(
    const unsigned short* __restrict__ A, const unsigned short* __restrict__ Bt,
    unsigned short* __restrict__ C, int M, int N, int K) {
    constexpr int NF = BN / 32;  // 16-col frags per wave
    __shared__ short As[128 * LDK];
    __shared__ short Bs[BN * LDK];
    int tid = threadIdx.x;
    int m0 = blockIdx.y * 128, n0 = blockIdx.x * BN;
    int lane = tid & 63, wid = tid >> 6;
    int wm = wid >> 1, wn = wid & 1;
    int r16 = lane & 15, kg = lane >> 4, k8 = kg * 8;

    f32x4 zero4 = {0.f, 0.f, 0.f, 0.f};
    f32x4 acc[4][NF];
#pragma unroll
    for (int m = 0; m < 4; ++m)
#pragma unroll
        for (int nn = 0; nn < NF; ++nn) acc[m][nn] = zero4;

    bf16x8 zv = {0, 0, 0, 0, 0, 0, 0, 0};

    for (int k0 = 0; k0 < K; k0 += 32) {
        // stage A: 128 rows x 32 cols = 512 chunks of 8 bf16
#pragma unroll
        for (int i = 0; i < 2; ++i) {
            int c = tid + i * 256;
            int row = c >> 2, off = (c & 3) * 8;
            bf16x8 v = zv;
            int gr = m0 + row, gc = k0 + off;
            if (gr < M && gc + 8 <= K)
                v = *(const bf16x8*)(const void*)(A + (size_t)gr * K + gc);
            *(bf16x8*)(void*)(&As[row * LDK + off]) = v;
        }
        // stage Bt: BN rows x 32 cols
#pragma unroll
        for (int i = 0; i < BN / 64; ++i) {
            int c = tid + i * 256;
            int row = c >> 2, off = (c & 3) * 8;
            bf16x8 v = zv;
            int gr = n0 + row, gc = k0 + off;
            if (gr < N && gc + 8 <= K)
                v = *(const bf16x8*)(const void*)(Bt + (size_t)gr * K + gc);
            *(bf16x8*)(void*)(&Bs[row * LDK + off]) = v;
        }
        __syncthreads();
        bf16x8 a[4], b[NF];
#pragma unroll
        for (int m = 0; m < 4; ++m)
            a[m] = *(const bf16x8*)(const void*)(&As[(wm * 64 + m * 16 + r16) * LDK + k8]);
#pragma unroll
        for (int nn = 0; nn < NF; ++nn)
            b[nn] = *(const bf16x8*)(const void*)(&Bs[(wn * (BN / 2) + nn * 16 + r16) * LDK + k8]);
#pragma unroll
        for (int m = 0; m < 4; ++m)
#pragma unroll
            for (int nn = 0; nn < NF; ++nn)
                acc[m][nn] = __builtin_amdgcn_mfma_f32_16x16x32_bf16(a[m], b[nn], acc[m][nn], 0, 0, 0);
        __syncthreads();
    }
#pragma unroll
    for (int m = 0; m < 4; ++m) {
        int row_base = m0 + wm * 64 + m * 16 + kg * 4;
#pragma unroll
        for (int nn = 0; nn < NF; ++nn) {
            int col = n0 + wn * (BN / 2) + nn * 16 + r16;
            if (col < N) {
#pragma unroll
                for (int r = 0; r < 4; ++r) {
                    int row = row_base + r;
                    if (row < M) C[(size_t)row * N + col] = f2b(acc[m][nn][r]);
                }
            }
        }
    }
}

// ---------------- attention left/right dot products (packed uint loads) ----------------
__global__ void elr_kernel(const unsigned short* __restrict__ h, const float* __restrict__ al,
                           const float* __restrict__ ar, float* __restrict__ el,
                           float* __restrict__ er, int H, int F) {
    int n = blockIdx.x;
    int lane = threadIdx.x & 63;
    int hh = threadIdx.x >> 6;
    const unsigned* row = (const unsigned*)(const void*)(h + (size_t)n * H * F + (size_t)hh * F);
    int F2 = F >> 1;
    float sl = 0.f, sr = 0.f;
    for (int f = lane; f < F2; f += 64) {
        unsigned u = row[f];
        float v0 = b2f((unsigned short)(u & 0xffffu));
        float v1 = b2f((unsigned short)(u >> 16));
        int c = hh * F + 2 * f;
        sl += v0 * al[c] + v1 * al[c + 1];
        sr += v0 * ar[c] + v1 * ar[c + 1];
    }
#pragma unroll
    for (int off = 32; off; off >>= 1) {
        sl += __shfl_down(sl, off);
        sr += __shfl_down(sr, off);
    }
    if (lane == 0) {
        el[n * H + hh] = sl;
        er[n * H + hh] = sr;
    }
}

// ---------------- fused edge-score + softmax -> alpha (CSR order) ----------------
template <int H>
__global__ __launch_bounds__(256) void alpha_kernel(
    const float* __restrict__ el, const float* __restrict__ er,
    const int* __restrict__ csrc, const int* __restrict__ offsets,
    float* __restrict__ alpha, int nnodes) {
    int n = blockIdx.x * 4 + (threadIdx.x >> 6);
    if (n >= nnodes) return;
    int lane = threadIdx.x & 63;
    int start = offsets[n], deg = offsets[n + 1] - start;
    if (deg == 0) return;
    float ern[H];
#pragma unroll
    for (int h = 0; h < H; ++h) ern[h] = er[n * H + h];

    if (deg <= 64) {
        bool act = lane < deg;
        float sh[H];
#pragma unroll
        for (int h = 0; h < H; ++h) sh[h] = -3.402823466e38f;
        if (act) {
            int sc = csrc[start + lane];
            if constexpr (H == 4) {
                float4 e4 = *(const float4*)(el + (size_t)sc * 4);
                float tv[4] = {e4.x, e4.y, e4.z, e4.w};
#pragma unroll
                for (int h = 0; h < 4; ++h) {
                    float v = tv[h] + ern[h];
                    sh[h] = v > 0.f ? v : 0.2f * v;
                }
            } else {
#pragma unroll
                for (int h = 0; h < H; ++h) {
                    float v = el[sc * H + h] + ern[h];
                    sh[h] = v > 0.f ? v : 0.2f * v;
                }
            }
        }
        float m[H], e[H], s[H];
#pragma unroll
        for (int h = 0; h < H; ++h) {
            m[h] = sh[h];
#pragma unroll
            for (int off = 32; off; off >>= 1) m[h] = fmaxf(m[h], __shfl_xor(m[h], off));
        }
#pragma unroll
        for (int h = 0; h < H; ++h) {
            e[h] = act ? expf(sh[h] - m[h]) : 0.f;
            s[h] = e[h];
#pragma unroll
            for (int off = 32; off; off >>= 1) s[h] += __shfl_xor(s[h], off);
        }
        if (act) {
            if constexpr (H == 4) {
                float4 o;
                o.x = e[0] / (s[0] + 1e-9f);
                o.y = e[1] / (s[1] + 1e-9f);
                o.z = e[2] / (s[2] + 1e-9f);
                o.w = e[3] / (s[3] + 1e-9f);
                *(float4*)(alpha + (size_t)(start + lane) * 4) = o;
            } else {
#pragma unroll
                for (int h = 0; h < H; ++h)
                    alpha[(size_t)(start + lane) * H + h] = e[h] / (s[h] + 1e-9f);
            }
        }
    } else {
        float m[H], s[H];
#pragma unroll
        for (int h = 0; h < H; ++h) { m[h] = -3.402823466e38f; s[h] = 0.f; }
        for (int c0 = 0; c0 < deg; c0 += 64) {
            if (c0 + lane < deg) {
                int sc = csrc[start + c0 + lane];
#pragma unroll
                for (int h = 0; h < H; ++h) {
                    float v = el[sc * H + h] + ern[h];
                    v = v > 0.f ? v : 0.2f * v;
                    m[h] = fmaxf(m[h], v);
                }
            }
        }
#pragma unroll
        for (int h = 0; h < H; ++h)
#pragma unroll
            for (int off = 32; off; off >>= 1) m[h] = fmaxf(m[h], __shfl_xor(m[h], off));
        for (int c0 = 0; c0 < deg; c0 += 64) {
            if (c0 + lane < deg) {
                int sc = csrc[start + c0 + lane];
#pragma unroll
                for (int h = 0; h < H; ++h) {
                    float v = el[sc * H + h] + ern[h];
                    v = v > 0.f ? v : 0.2f * v;
                    s[h] += expf(v - m[h]);
                }
            }
        }
#pragma unroll
        for (int h = 0; h < H; ++h)
#pragma unroll
            for (int off = 32; off; off >>= 1) s[h] += __shfl_xor(s[h], off);
        for (int c0 = 0; c0 < deg; c0 += 64) {
            if (c0 + lane < deg) {
                int sc = csrc[start + c0 + lane];
#pragma unroll
                for (int h = 0; h < H; ++h) {
                    float v = el[sc * H + h] + ern[h];
                    v = v > 0.f ? v : 0.2f * v;
                    alpha[(size_t)(start + c0 + lane) * H + h] = expf(v - m[h]) / (s[h] + 1e-9f);
                }
            }
        }
    }
}

// ---------------- per-dst weighted aggregation (bf16 gather) ----------------
// ACT: 0 = ELU -> bf16 out, 1 = sigmoid -> f32 out. NC = HF/8 chunks, P edge
// groups, BS = block size.
template <int ACT, int H, int NC, int P, int BS>
__global__ __launch_bounds__(BS) void aggregate_kernel(
    const unsigned short* __restrict__ hC, const float* __restrict__ alpha,
    const int* __restrict__ offsets, const int* __restrict__ csrc,
    const float* __restrict__ bias, void* __restrict__ out) {
    constexpr int HF = NC * 8;
    constexpr int F = HF / H;
    int n = blockIdx.x;
    int tid = threadIdx.x;
    int start = offsets[n], deg = offsets[n + 1] - start;

    __shared__ int s_src[64];
    __shared__ float s_alpha[64 * H];
    __shared__ float s_part[(P > 1 ? (P - 1) : 1) * NC * 8];

    bool active = tid < NC * P;
    int slot = tid % NC;
    int q = tid / NC;
    int h0 = (slot * 8) / F, h1 = (slot * 8 + 7) / F;
    int split = (h0 == h1) ? 8 : (h1 * F - slot * 8);
    float acc[8] = {0.f, 0.f, 0.f, 0.f, 0.f, 0.f, 0.f, 0.f};

    for (int c0 = 0; c0 < deg; c0 += 64) {
        int cn = min(64, deg - c0);
        if (tid < cn) {
            s_src[tid] = csrc[start + c0 + tid];
            if constexpr (H == 4) {
                float4 a4 = *(const float4*)(alpha + (size_t)(start + c0 + tid) * 4);
                *(float4*)(&s_alpha[tid * 4]) = a4;
            } else {
                s_alpha[tid] = alpha[start + c0 + tid];
            }
        }
        __syncthreads();
        if (active) {
            for (int k = q; k < cn; k += P) {
                const unsigned short* row = hC + (size_t)s_src[k] * HF;
                bf16x8 v = *(const bf16x8*)(const void*)(row + slot * 8);
                float a0 = s_alpha[k * H + h0];
                float a1 = s_alpha[k * H + h1];
#pragma unroll
                for (int j = 0; j < 8; ++j) {
                    float a = (j < split) ? a0 : a1;
                    acc[j] += b2f((unsigned short)v[j]) * a;
                }
            }
        }
        __syncthreads();
    }

    if constexpr (P > 1) {
        if (active && q > 0) {
#pragma unroll
            for (int j = 0; j < 8; ++j) s_part[((q - 1) * NC + slot) * 8 + j] = acc[j];
        }
        __syncthreads();
        if (tid < NC) {
            for (int qq = 1; qq < P; ++qq)
#pragma unroll
                for (int j = 0; j < 8; ++j) acc[j] += s_part[((qq - 1) * NC + slot) * 8 + j];
        }
    }

    if (tid < NC) {
        float4 bA = *(const float4*)(bias + slot * 8);
        float4 bB = *(const float4*)(bias + slot * 8 + 4);
        float bb[8] = {bA.x, bA.y, bA.z, bA.w, bB.x, bB.y, bB.z, bB.w};
        float v[8];
#pragma unroll
        for (int j = 0; j < 8; ++j) v[j] = acc[j] + bb[j];
        if (ACT == 0) {
            bf16x8 u;
#pragma unroll
            for (int j = 0; j < 8; ++j) {
                float w = v[j] > 0.f ? v[j] : expm1f(v[j]);
                u[j] = (short)f2b(w);
            }
            *(bf16x8*)(void*)((unsigned short*)out + (size_t)n * HF + slot * 8) = u;
        } else {
            float4 oA, oB;
            oA.x = 1.f / (1.f + expf(-v[0]));
            oA.y = 1.f / (1.f + expf(-v[1]));
            oA.z = 1.f / (1.f + expf(-v[2]));
            oA.w = 1.f / (1.f + expf(-v[3]));
            oB.x = 1.f / (1.f + expf(-v[4]));
            oB.y = 1.f / (1.f + expf(-v[5]));
            oB.z = 1.f / (1.f + expf(-v[6]));
            oB.w = 1.f / (1.f + expf(-v[7]));
            float* op = (float*)out + (size_t)n * HF + slot * 8;
            *(float4*)op = oA;
            *(float4*)(op + 4) = oB;
        }
    }
}

// ---------------- launch ----------------

extern "C" void kernel_launch(void* const* d_in, const int* in_sizes, int n_in,
                              void* d_out, int out_size, void* d_ws, size_t ws_size,
                              hipStream_t stream) {
    const float* x   = (const float*)d_in[0];
    const int*   src = (const int*)d_in[1];
    const int*   dst = (const int*)d_in[2];
    const float* W1  = (const float*)d_in[3];
    const float* al1 = (const float*)d_in[4];
    const float* ar1 = (const float*)d_in[5];
    const float* b1  = (const float*)d_in[6];
    const float* W2  = (const float*)d_in[7];
    const float* al2 = (const float*)d_in[8];
    const float* ar2 = (const float*)d_in[9];
    const float* b2  = (const float*)d_in[10];
    const float* W3  = (const float*)d_in[11];
    const float* al3 = (const float*)d_in[12];
    const float* ar3 = (const float*)d_in[13];
    const float* b3  = (const float*)d_in[14];
    float* out = (float*)d_out;

    char* ws = (char*)d_ws;
    size_t off = 0;
    auto alloc = [&](size_t bytes) -> char* {
        char* p = ws + off;
        off += (bytes + 255) & ~(size_t)255;
        return p;
    };
    int* offsets = (int*)alloc((N_NODES + 1) * sizeof(int));
    int* cursor  = (int*)alloc(N_NODES * sizeof(int));
    int* deg     = (int*)alloc(N_NODES * sizeof(int));
    int* csrc    = (int*)alloc(N_EDGES * sizeof(int));
    float* el    = (float*)alloc((size_t)N_NODES * 4 * sizeof(float));
    float* er    = (float*)alloc((size_t)N_NODES * 4 * sizeof(float));
    float* alpha = (float*)alloc((size_t)N_EDGES * 4 * sizeof(float));
    unsigned short* bufX = (unsigned short*)alloc((size_t)N_NODES * 800 * 2);
    unsigned short* bufH = (unsigned short*)alloc((size_t)N_NODES * 800 * 2);
    unsigned short* Wt   = (unsigned short*)alloc((size_t)800 * 400 * 2);

    // CSR build (dst-indexed)
    zero_ints<<<(N_NODES + 255) / 256, 256, 0, stream>>>(deg, N_NODES);
    zero_ints<<<(N_NODES + 255) / 256, 256, 0, stream>>>(cursor, N_NODES);
    hist_kernel<<<(N_EDGES + 255) / 256, 256, 0, stream>>>(dst, deg);
    scan_kernel<<<1, SCAN_T, 0, stream>>>(deg, offsets);
    scatter_kernel<<<(N_EDGES + 255) / 256, 256, 0, stream>>>(dst, src, offsets, cursor, csrc);

    // x -> bf16
    castx_kernel<<<(N_NODES * 128 / 4 + 255) / 256, 256, 0, stream>>>(x, bufX, N_NODES * 128 / 4);

    // ---- layer 1: [20000,128]x[128,400], H=4 F=100, ELU ----
    {
        int K = 128, N = 400, H = 4, F = 100;
        wcast_kernel<<<(K * N + 255) / 256, 256, 0, stream>>>(W1, Wt, K, N);
        dim3 grid((N + 127) / 128, (N_NODES + 127) / 128);
        gemm_mfma<128><<<grid, 256, 0, stream>>>(bufX, Wt, bufH, N_NODES, N, K);
        elr_kernel<<<N_NODES, H * 64, 0, stream>>>(bufH, al1, ar1, el, er, H, F);
        alpha_kernel<4><<<(N_NODES + 3) / 4, 256, 0, stream>>>(el, er, csrc, offsets, alpha, N_NODES);
        aggregate_kernel<0, 4, 50, 10, 512><<<N_NODES, 512, 0, stream>>>(bufH, alpha, offsets, csrc, b1, bufX);
    }
    // ---- layer 2: [20000,400]x[400,800], H=4 F=200, ELU ----
    {
        int K = 400, N = 800, H = 4, F = 200;
        wcast_kernel<<<(K * N + 255) / 256, 256, 0, stream>>>(W2, Wt, K, N);
        dim3 grid((N + 127) / 128, (N_NODES + 127) / 128);
        gemm_mfma<128><<<grid, 256, 0, stream>>>(bufX, Wt, bufH, N_NODES, N, K);
        elr_kernel<<<N_NODES, H * 64, 0, stream>>>(bufH, al2, ar2, el, er, H, F);
        alpha_kernel<4><<<(N_NODES + 3) / 4, 256, 0, stream>>>(el, er, csrc, offsets, alpha, N_NODES);
        aggregate_kernel<0, 4, 100, 5, 512><<<N_NODES, 512, 0, stream>>>(bufH, alpha, offsets, csrc, b2, bufX);
    }
    // ---- layer 3: [20000,800]x[800,64], H=1 F=64, sigmoid -> d_out ----
    {
        int K = 800, N = 64, F = 64;
        wcast_kernel<<<(K * N + 255) / 256, 256, 0, stream>>>(W3, Wt, K, N);
        dim3 grid(1, (N_NODES + 127) / 128);
        gemm_mfma<64><<<grid, 256, 0, stream>>>(bufX, Wt, bufH, N_NODES, N, K);
        elr_kernel<<<N_NODES, 64, 0, stream>>>(bufH, al3, ar3, el, er, 1, F);
        alpha_kernel<1><<<(N_NODES + 3) / 4, 256, 0, stream>>>(el, er, csrc, offsets, alpha, N_NODES);
        aggregate_kernel<1, 1, 8, 32, 256><<<N_NODES, 256, 0, stream>>>(bufH, alpha, offsets, csrc, b3, out);
    }
}

// Round 10
// 426.714 us; speedup vs baseline: 1.4507x; 1.1625x over previous
//
#include <hip/hip_runtime.h>
#include <math.h>

#define N_NODES 20000
#define N_EDGES 256000

typedef __attribute__((ext_vector_type(8))) short bf16x8;
typedef __attribute__((ext_vector_type(4))) float f32x4;

__device__ inline unsigned short f2b(float f) {
    unsigned u = __builtin_bit_cast(unsigned, f);
    unsigned r = (u + 0x7fffu + ((u >> 16) & 1u)) >> 16;
    return (unsigned short)r;
}
__device__ inline float b2f(unsigned short s) {
    return __builtin_bit_cast(float, ((unsigned)s) << 16);
}

// ---------------- CSR build ----------------

__global__ void zero_ints(int* __restrict__ a, int n) {
    int i = blockIdx.x * blockDim.x + threadIdx.x;
    if (i < n) a[i] = 0;
}

__global__ void hist_kernel(const int* __restrict__ dst, int* __restrict__ deg) {
    int i = blockIdx.x * blockDim.x + threadIdx.x;
    if (i < N_EDGES) atomicAdd(&deg[dst[i]], 1);
}

#define SCAN_T 1024
#define SCAN_CH 20

__global__ __launch_bounds__(1024) void scan_kernel(const int* __restrict__ deg,
                                                    int* __restrict__ offsets) {
    __shared__ int sums[SCAN_T];
    int tid = threadIdx.x;
    int base = tid * SCAN_CH;
    int vals[SCAN_CH];
    int local = 0;
#pragma unroll
    for (int i = 0; i < SCAN_CH; ++i) {
        int idx = base + i;
        int v = (idx < N_NODES) ? deg[idx] : 0;
        vals[i] = v;
        local += v;
    }
    sums[tid] = local;
    __syncthreads();
    for (int off = 1; off < SCAN_T; off <<= 1) {
        int t = (tid >= off) ? sums[tid - off] : 0;
        __syncthreads();
        sums[tid] += t;
        __syncthreads();
    }
    int run = (tid > 0) ? sums[tid - 1] : 0;
    if (tid == 0) offsets[0] = 0;
#pragma unroll
    for (int i = 0; i < SCAN_CH; ++i) {
        int idx = base + i;
        if (idx < N_NODES) {
            run += vals[i];
            offsets[idx + 1] = run;
        }
    }
}

__global__ void scatter_kernel(const int* __restrict__ dst, const int* __restrict__ src,
                               const int* __restrict__ offsets,
                               int* __restrict__ cursor, int* __restrict__ csrc) {
    int i = blockIdx.x * blockDim.x + threadIdx.x;
    if (i < N_EDGES) {
        int d = dst[i];
        int p = offsets[d] + atomicAdd(&cursor[d], 1);
        csrc[p] = src[i];
    }
}

// ---------------- casts ----------------

__global__ void castx_kernel(const float* __restrict__ in, unsigned short* __restrict__ out, int n4) {
    int i = blockIdx.x * blockDim.x + threadIdx.x;
    if (i < n4) {
        float4 v = ((const float4*)in)[i];
        ushort4 u;
        u.x = f2b(v.x); u.y = f2b(v.y); u.z = f2b(v.z); u.w = f2b(v.w);
        ((ushort4*)out)[i] = u;
    }
}

// Wt[n][k] = bf16(W[k][n]); W is [K][N] row-major
__global__ void wcast_kernel(const float* __restrict__ W, unsigned short* __restrict__ Wt,
                             int K, int N) {
    int id = blockIdx.x * blockDim.x + threadIdx.x;
    if (id < K * N) {
        int n = id / K, k = id - n * K;
        Wt[id] = f2b(W[(size_t)k * N + n]);
    }
}

// ---------------- bf16 MFMA GEMM: C[M,N](bf16) = A[M,K] * Bt[N,K]^T ----------------
// 128xBN tile, BK=32, 4 waves (2x2); per-wave 64 x BN/2 (4 x BN/32 frags of 16x16x32)

#define LDK 40  // 32 + 8 pad (bf16 elems); 80B row stride keeps ds_read_b128 ~conflict-free

template <int BN>
__global__ __launch_bounds__(256) void gemm_mfma(
    const unsigned short* __restrict__ A, const unsigned short* __restrict__ Bt,
    unsigned short* __restrict__ C, int M, int N, int K) {
    constexpr int NF = BN / 32;  // 16-col frags per wave
    __shared__ short As[128 * LDK];
    __shared__ short Bs[BN * LDK];
    int tid = threadIdx.x;
    int m0 = blockIdx.y * 128, n0 = blockIdx.x * BN;
    int lane = tid & 63, wid = tid >> 6;
    int wm = wid >> 1, wn = wid & 1;
    int r16 = lane & 15, kg = lane >> 4, k8 = kg * 8;

    f32x4 zero4 = {0.f, 0.f, 0.f, 0.f};
    f32x4 acc[4][NF];
#pragma unroll
    for (int m = 0; m < 4; ++m)
#pragma unroll
        for (int nn = 0; nn < NF; ++nn) acc[m][nn] = zero4;

    bf16x8 zv = {0, 0, 0, 0, 0, 0, 0, 0};

    for (int k0 = 0; k0 < K; k0 += 32) {
        // stage A: 128 rows x 32 cols = 512 chunks of 8 bf16
#pragma unroll
        for (int i = 0; i < 2; ++i) {
            int c = tid + i * 256;
            int row = c >> 2, off = (c & 3) * 8;
            bf16x8 v = zv;
            int gr = m0 + row, gc = k0 + off;
            if (gr < M && gc + 8 <= K)
                v = *(const bf16x8*)(const void*)(A + (size_t)gr * K + gc);
            *(bf16x8*)(void*)(&As[row * LDK + off]) = v;
        }
        // stage Bt: BN rows x 32 cols
#pragma unroll
        for (int i = 0; i < BN / 64; ++i) {
            int c = tid + i * 256;
            int row = c >> 2, off = (c & 3) * 8;
            bf16x8 v = zv;
            int gr = n0 + row, gc = k0 + off;
            if (gr < N && gc + 8 <= K)
                v = *(const bf16x8*)(const void*)(Bt + (size_t)gr * K + gc);
            *(bf16x8*)(void*)(&Bs[row * LDK + off]) = v;
        }
        __syncthreads();
        bf16x8 a[4], b[NF];
#pragma unroll
        for (int m = 0; m < 4; ++m)
            a[m] = *(const bf16x8*)(const void*)(&As[(wm * 64 + m * 16 + r16) * LDK + k8]);
#pragma unroll
        for (int nn = 0; nn < NF; ++nn)
            b[nn] = *(const bf16x8*)(const void*)(&Bs[(wn * (BN / 2) + nn * 16 + r16) * LDK + k8]);
#pragma unroll
        for (int m = 0; m < 4; ++m)
#pragma unroll
            for (int nn = 0; nn < NF; ++nn)
                acc[m][nn] = __builtin_amdgcn_mfma_f32_16x16x32_bf16(a[m], b[nn], acc[m][nn], 0, 0, 0);
        __syncthreads();
    }
#pragma unroll
    for (int m = 0; m < 4; ++m) {
        int row_base = m0 + wm * 64 + m * 16 + kg * 4;
#pragma unroll
        for (int nn = 0; nn < NF; ++nn) {
            int col = n0 + wn * (BN / 2) + nn * 16 + r16;
            if (col < N) {
#pragma unroll
                for (int r = 0; r < 4; ++r) {
                    int row = row_base + r;
                    if (row < M) C[(size_t)row * N + col] = f2b(acc[m][nn][r]);
                }
            }
        }
    }
}

// ---------------- attention left/right dot products (packed uint loads) ----------------
__global__ void elr_kernel(const unsigned short* __restrict__ h, const float* __restrict__ al,
                           const float* __restrict__ ar, float* __restrict__ el,
                           float* __restrict__ er, int H, int F) {
    int n = blockIdx.x;
    int lane = threadIdx.x & 63;
    int hh = threadIdx.x >> 6;
    const unsigned* row = (const unsigned*)(const void*)(h + (size_t)n * H * F + (size_t)hh * F);
    int F2 = F >> 1;
    float sl = 0.f, sr = 0.f;
    for (int f = lane; f < F2; f += 64) {
        unsigned u = row[f];
        float v0 = b2f((unsigned short)(u & 0xffffu));
        float v1 = b2f((unsigned short)(u >> 16));
        int c = hh * F + 2 * f;
        sl += v0 * al[c] + v1 * al[c + 1];
        sr += v0 * ar[c] + v1 * ar[c + 1];
    }
#pragma unroll
    for (int off = 32; off; off >>= 1) {
        sl += __shfl_down(sl, off);
        sr += __shfl_down(sr, off);
    }
    if (lane == 0) {
        el[n * H + hh] = sl;
        er[n * H + hh] = sr;
    }
}

// ---------------- fused edge-score + softmax -> alpha (CSR order) ----------------
template <int H>
__global__ __launch_bounds__(256) void alpha_kernel(
    const float* __restrict__ el, const float* __restrict__ er,
    const int* __restrict__ csrc, const int* __restrict__ offsets,
    float* __restrict__ alpha, int nnodes) {
    int n = blockIdx.x * 4 + (threadIdx.x >> 6);
    if (n >= nnodes) return;
    int lane = threadIdx.x & 63;
    int start = offsets[n], deg = offsets[n + 1] - start;
    if (deg == 0) return;
    float ern[H];
#pragma unroll
    for (int h = 0; h < H; ++h) ern[h] = er[n * H + h];

    if (deg <= 64) {
        bool act = lane < deg;
        float sh[H];
#pragma unroll
        for (int h = 0; h < H; ++h) sh[h] = -3.402823466e38f;
        if (act) {
            int sc = csrc[start + lane];
            if constexpr (H == 4) {
                float4 e4 = *(const float4*)(el + (size_t)sc * 4);
                float tv[4] = {e4.x, e4.y, e4.z, e4.w};
#pragma unroll
                for (int h = 0; h < 4; ++h) {
                    float v = tv[h] + ern[h];
                    sh[h] = v > 0.f ? v : 0.2f * v;
                }
            } else {
#pragma unroll
                for (int h = 0; h < H; ++h) {
                    float v = el[sc * H + h] + ern[h];
                    sh[h] = v > 0.f ? v : 0.2f * v;
                }
            }
        }
        float m[H], e[H], s[H];
#pragma unroll
        for (int h = 0; h < H; ++h) {
            m[h] = sh[h];
#pragma unroll
            for (int off = 32; off; off >>= 1) m[h] = fmaxf(m[h], __shfl_xor(m[h], off));
        }
#pragma unroll
        for (int h = 0; h < H; ++h) {
            e[h] = act ? expf(sh[h] - m[h]) : 0.f;
            s[h] = e[h];
#pragma unroll
            for (int off = 32; off; off >>= 1) s[h] += __shfl_xor(s[h], off);
        }
        if (act) {
            if constexpr (H == 4) {
                float4 o;
                o.x = e[0] / (s[0] + 1e-9f);
                o.y = e[1] / (s[1] + 1e-9f);
                o.z = e[2] / (s[2] + 1e-9f);
                o.w = e[3] / (s[3] + 1e-9f);
                *(float4*)(alpha + (size_t)(start + lane) * 4) = o;
            } else {
#pragma unroll
                for (int h = 0; h < H; ++h)
                    alpha[(size_t)(start + lane) * H + h] = e[h] / (s[h] + 1e-9f);
            }
        }
    } else {
        float m[H], s[H];
#pragma unroll
        for (int h = 0; h < H; ++h) { m[h] = -3.402823466e38f; s[h] = 0.f; }
        for (int c0 = 0; c0 < deg; c0 += 64) {
            if (c0 + lane < deg) {
                int sc = csrc[start + c0 + lane];
#pragma unroll
                for (int h = 0; h < H; ++h) {
                    float v = el[sc * H + h] + ern[h];
                    v = v > 0.f ? v : 0.2f * v;
                    m[h] = fmaxf(m[h], v);
                }
            }
        }
#pragma unroll
        for (int h = 0; h < H; ++h)
#pragma unroll
            for (int off = 32; off; off >>= 1) m[h] = fmaxf(m[h], __shfl_xor(m[h], off));
        for (int c0 = 0; c0 < deg; c0 += 64) {
            if (c0 + lane < deg) {
                int sc = csrc[start + c0 + lane];
#pragma unroll
                for (int h = 0; h < H; ++h) {
                    float v = el[sc * H + h] + ern[h];
                    v = v > 0.f ? v : 0.2f * v;
                    s[h] += expf(v - m[h]);
                }
            }
        }
#pragma unroll
        for (int h = 0; h < H; ++h)
#pragma unroll
            for (int off = 32; off; off >>= 1) s[h] += __shfl_xor(s[h], off);
        for (int c0 = 0; c0 < deg; c0 += 64) {
            if (c0 + lane < deg) {
                int sc = csrc[start + c0 + lane];
#pragma unroll
                for (int h = 0; h < H; ++h) {
                    float v = el[sc * H + h] + ern[h];
                    v = v > 0.f ? v : 0.2f * v;
                    alpha[(size_t)(start + c0 + lane) * H + h] = expf(v - m[h]) / (s[h] + 1e-9f);
                }
            }
        }
    }
}

// ---------------- per-dst weighted aggregation (bf16 gather) ----------------
// ACT: 0 = ELU -> bf16 out, 1 = sigmoid -> f32 out. NC = HF/8 chunks, P edge
// groups, BS = block size.
template <int ACT, int H, int NC, int P, int BS>
__global__ __launch_bounds__(BS) void aggregate_kernel(
    const unsigned short* __restrict__ hC, const float* __restrict__ alpha,
    const int* __restrict__ offsets, const int* __restrict__ csrc,
    const float* __restrict__ bias, void* __restrict__ out) {
    constexpr int HF = NC * 8;
    constexpr int F = HF / H;
    int n = blockIdx.x;
    int tid = threadIdx.x;
    int start = offsets[n], deg = offsets[n + 1] - start;

    __shared__ int s_src[64];
    __shared__ float s_alpha[64 * H];
    __shared__ float s_part[(P > 1 ? (P - 1) : 1) * NC * 8];

    bool active = tid < NC * P;
    int slot = tid % NC;
    int q = tid / NC;
    int h0 = (slot * 8) / F, h1 = (slot * 8 + 7) / F;
    int split = (h0 == h1) ? 8 : (h1 * F - slot * 8);
    float acc[8] = {0.f, 0.f, 0.f, 0.f, 0.f, 0.f, 0.f, 0.f};

    for (int c0 = 0; c0 < deg; c0 += 64) {
        int cn = min(64, deg - c0);
        if (tid < cn) {
            s_src[tid] = csrc[start + c0 + tid];
            if constexpr (H == 4) {
                float4 a4 = *(const float4*)(alpha + (size_t)(start + c0 + tid) * 4);
                *(float4*)(&s_alpha[tid * 4]) = a4;
            } else {
                s_alpha[tid] = alpha[start + c0 + tid];
            }
        }
        __syncthreads();
        if (active) {
            for (int k = q; k < cn; k += P) {
                const unsigned short* row = hC + (size_t)s_src[k] * HF;
                bf16x8 v = *(const bf16x8*)(const void*)(row + slot * 8);
                float a0 = s_alpha[k * H + h0];
                float a1 = s_alpha[k * H + h1];
#pragma unroll
                for (int j = 0; j < 8; ++j) {
                    float a = (j < split) ? a0 : a1;
                    acc[j] += b2f((unsigned short)v[j]) * a;
                }
            }
        }
        __syncthreads();
    }

    if constexpr (P > 1) {
        if (active && q > 0) {
#pragma unroll
            for (int j = 0; j < 8; ++j) s_part[((q - 1) * NC + slot) * 8 + j] = acc[j];
        }
        __syncthreads();
        if (tid < NC) {
            for (int qq = 1; qq < P; ++qq)
#pragma unroll
                for (int j = 0; j < 8; ++j) acc[j] += s_part[((qq - 1) * NC + slot) * 8 + j];
        }
    }

    if (tid < NC) {
        float4 bA = *(const float4*)(bias + slot * 8);
        float4 bB = *(const float4*)(bias + slot * 8 + 4);
        float bb[8] = {bA.x, bA.y, bA.z, bA.w, bB.x, bB.y, bB.z, bB.w};
        float v[8];
#pragma unroll
        for (int j = 0; j < 8; ++j) v[j] = acc[j] + bb[j];
        if (ACT == 0) {
            bf16x8 u;
#pragma unroll
            for (int j = 0; j < 8; ++j) {
                float w = v[j] > 0.f ? v[j] : expm1f(v[j]);
                u[j] = (short)f2b(w);
            }
            *(bf16x8*)(void*)((unsigned short*)out + (size_t)n * HF + slot * 8) = u;
        } else {
            float4 oA, oB;
            oA.x = 1.f / (1.f + expf(-v[0]));
            oA.y = 1.f / (1.f + expf(-v[1]));
            oA.z = 1.f / (1.f + expf(-v[2]));
            oA.w = 1.f / (1.f + expf(-v[3]));
            oB.x = 1.f / (1.f + expf(-v[4]));
            oB.y = 1.f / (1.f + expf(-v[5]));
            oB.z = 1.f / (1.f + expf(-v[6]));
            oB.w = 1.f / (1.f + expf(-v[7]));
            float* op = (float*)out + (size_t)n * HF + slot * 8;
            *(float4*)op = oA;
            *(float4*)(op + 4) = oB;
        }
    }
}

// ---------------- launch ----------------

extern "C" void kernel_launch(void* const* d_in, const int* in_sizes, int n_in,
                              void* d_out, int out_size, void* d_ws, size_t ws_size,
                              hipStream_t stream) {
    const float* x   = (const float*)d_in[0];
    const int*   src = (const int*)d_in[1];
    const int*   dst = (const int*)d_in[2];
    const float* W1  = (const float*)d_in[3];
    const float* al1 = (const float*)d_in[4];
    const float* ar1 = (const float*)d_in[5];
    const float* b1  = (const float*)d_in[6];
    const float* W2  = (const float*)d_in[7];
    const float* al2 = (const float*)d_in[8];
    const float* ar2 = (const float*)d_in[9];
    const float* b2  = (const float*)d_in[10];
    const float* W3  = (const float*)d_in[11];
    const float* al3 = (const float*)d_in[12];
    const float* ar3 = (const float*)d_in[13];
    const float* b3  = (const float*)d_in[14];
    float* out = (float*)d_out;

    char* ws = (char*)d_ws;
    size_t off = 0;
    auto alloc = [&](size_t bytes) -> char* {
        char* p = ws + off;
        off += (bytes + 255) & ~(size_t)255;
        return p;
    };
    int* offsets = (int*)alloc((N_NODES + 1) * sizeof(int));
    int* cursor  = (int*)alloc(N_NODES * sizeof(int));
    int* deg     = (int*)alloc(N_NODES * sizeof(int));
    int* csrc    = (int*)alloc(N_EDGES * sizeof(int));
    float* el    = (float*)alloc((size_t)N_NODES * 4 * sizeof(float));
    float* er    = (float*)alloc((size_t)N_NODES * 4 * sizeof(float));
    float* alpha = (float*)alloc((size_t)N_EDGES * 4 * sizeof(float));
    unsigned short* bufX = (unsigned short*)alloc((size_t)N_NODES * 800 * 2);
    unsigned short* bufH = (unsigned short*)alloc((size_t)N_NODES * 800 * 2);
    unsigned short* Wt   = (unsigned short*)alloc((size_t)800 * 400 * 2);

    // CSR build (dst-indexed)
    zero_ints<<<(N_NODES + 255) / 256, 256, 0, stream>>>(deg, N_NODES);
    zero_ints<<<(N_NODES + 255) / 256, 256, 0, stream>>>(cursor, N_NODES);
    hist_kernel<<<(N_EDGES + 255) / 256, 256, 0, stream>>>(dst, deg);
    scan_kernel<<<1, SCAN_T, 0, stream>>>(deg, offsets);
    scatter_kernel<<<(N_EDGES + 255) / 256, 256, 0, stream>>>(dst, src, offsets, cursor, csrc);

    // x -> bf16
    castx_kernel<<<(N_NODES * 128 / 4 + 255) / 256, 256, 0, stream>>>(x, bufX, N_NODES * 128 / 4);

    // ---- layer 1: [20000,128]x[128,400], H=4 F=100, ELU ----
    {
        int K = 128, N = 400, H = 4, F = 100;
        wcast_kernel<<<(K * N + 255) / 256, 256, 0, stream>>>(W1, Wt, K, N);
        dim3 grid((N + 127) / 128, (N_NODES + 127) / 128);
        gemm_mfma<128><<<grid, 256, 0, stream>>>(bufX, Wt, bufH, N_NODES, N, K);
        elr_kernel<<<N_NODES, H * 64, 0, stream>>>(bufH, al1, ar1, el, er, H, F);
        alpha_kernel<4><<<(N_NODES + 3) / 4, 256, 0, stream>>>(el, er, csrc, offsets, alpha, N_NODES);
        aggregate_kernel<0, 4, 50, 4, 256><<<N_NODES, 256, 0, stream>>>(bufH, alpha, offsets, csrc, b1, bufX);
    }
    // ---- layer 2: [20000,400]x[400,800], H=4 F=200, ELU ----
    {
        int K = 400, N = 800, H = 4, F = 200;
        wcast_kernel<<<(K * N + 255) / 256, 256, 0, stream>>>(W2, Wt, K, N);
        dim3 grid((N + 127) / 128, (N_NODES + 127) / 128);
        gemm_mfma<128><<<grid, 256, 0, stream>>>(bufX, Wt, bufH, N_NODES, N, K);
        elr_kernel<<<N_NODES, H * 64, 0, stream>>>(bufH, al2, ar2, el, er, H, F);
        alpha_kernel<4><<<(N_NODES + 3) / 4, 256, 0, stream>>>(el, er, csrc, offsets, alpha, N_NODES);
        aggregate_kernel<0, 4, 100, 2, 256><<<N_NODES, 256, 0, stream>>>(bufH, alpha, offsets, csrc, b2, bufX);
    }
    // ---- layer 3: [20000,800]x[800,64], H=1 F=64, sigmoid -> d_out ----
    {
        int K = 800, N = 64, F = 64;
        wcast_kernel<<<(K * N + 255) / 256, 256, 0, stream>>>(W3, Wt, K, N);
        dim3 grid(1, (N_NODES + 127) / 128);
        gemm_mfma<64><<<grid, 256, 0, stream>>>(bufX, Wt, bufH, N_NODES, N, K);
        elr_kernel<<<N_NODES, 64, 0, stream>>>(bufH, al3, ar3, el, er, 1, F);
        alpha_kernel<1><<<(N_NODES + 3) / 4, 256, 0, stream>>>(el, er, csrc, offsets, alpha, N_NODES);
        aggregate_kernel<1, 1, 8, 8, 256><<<N_NODES, 256, 0, stream>>>(bufH, alpha, offsets, csrc, b3, out);
    }
}